// Round 6
// baseline (460.022 us; speedup 1.0000x reference)
//
#include <hip/hip_runtime.h>
#include <cstdint>
#include <cstddef>

#define BN_EPS 1e-5f
#define NBLK 256
#define EPBMAX 6400
#define BCAP 4096
#define NBANK 32

typedef __attribute__((ext_vector_type(8))) short  bf16x8;
typedef __attribute__((ext_vector_type(4))) float  f32x4;
typedef __attribute__((ext_vector_type(8))) unsigned short ushort8;

__device__ __forceinline__ float bf2f(unsigned short u) {
  union { unsigned int i; float f; } c; c.i = ((unsigned int)u) << 16; return c.f;
}
__device__ __forceinline__ unsigned short f2bf(float f) {
  union { float f; unsigned int i; } c; c.f = f;
  unsigned int u = c.i;
  return (unsigned short)((u + 0x7FFFu + ((u >> 16) & 1u)) >> 16);  // RNE
}

// ---------------- graph partition (+ fused weight-convert blocks) ----------------
__global__ __launch_bounds__(256) void k_part(const int* __restrict__ src, const int* __restrict__ dst, int e, int epb,
                                              int* __restrict__ pairsG, int* __restrict__ cntT, int* __restrict__ scanT,
                                              int* __restrict__ totals,
                                              const float* __restrict__ W1, const float* __restrict__ W2,
                                              const float* __restrict__ W3,
                                              unsigned short* __restrict__ Wt1, unsigned short* __restrict__ Wt2,
                                              unsigned short* __restrict__ Wt3) {
  int b = blockIdx.x, tid = threadIdx.x;
  if (b >= NBLK) {           // fused cvtw: f32 [K][N] -> bf16 [N][K]
    int bb = b - NBLK;
    if (bb < 64)       { int idx = bb * 256 + tid;        Wt1[(idx & 127) * 128 + (idx >> 7)] = f2bf(W1[idx]); }
    else if (bb < 128) { int idx = (bb - 64) * 256 + tid; Wt2[(idx & 127) * 128 + (idx >> 7)] = f2bf(W2[idx]); }
    else               { int idx = (bb - 128) * 256 + tid; Wt3[(idx & 63) * 384 + (idx >> 6)] = f2bf(W3[idx]); }
    return;
  }
  __shared__ int sbuf[EPBMAX];
  __shared__ int hist[1024];
  __shared__ int base[1024];
  __shared__ int tmp[256];
  int e0 = b * epb, e1 = min(e0 + epb, e);
  for (int i = tid; i < 1024; i += 256) hist[i] = 0;
  __syncthreads();
  for (int i = e0 + tid; i < e1; i += 256) atomicAdd(&hist[dst[i] >> 7], 1);
  __syncthreads();
  for (int i = tid; i < 1024; i += 256) { int h = hist[i]; if (h) atomicAdd(&totals[i], h); }
  int c0 = hist[tid * 4], c1 = hist[tid * 4 + 1], c2 = hist[tid * 4 + 2], c3 = hist[tid * 4 + 3];
  int lsum = c0 + c1 + c2 + c3;
  tmp[tid] = lsum; __syncthreads();
  for (int off = 1; off < 256; off <<= 1) {
    int t = (tid >= off) ? tmp[tid - off] : 0; __syncthreads();
    tmp[tid] += t; __syncthreads();
  }
  int excl = tmp[tid] - lsum;
  base[tid * 4] = excl; base[tid * 4 + 1] = excl + c0;
  base[tid * 4 + 2] = excl + c0 + c1; base[tid * 4 + 3] = excl + c0 + c1 + c2;
  *(int4*)(cntT + b * 1024 + tid * 4) = make_int4(c0, c1, c2, c3);
  *(int4*)(scanT + b * 1024 + tid * 4) = make_int4(base[tid * 4], base[tid * 4 + 1], base[tid * 4 + 2], base[tid * 4 + 3]);
  __syncthreads();
  for (int i = e0 + tid; i < e1; i += 256) {
    int d = dst[i], s = src[i];
    int p = atomicAdd(&base[d >> 7], 1);
    sbuf[p] = ((d & 127) << 25) | s;
  }
  __syncthreads();
  int cnt = e1 - e0;
  for (int i = tid; i < cnt; i += 256) pairsG[e0 + i] = sbuf[i];
}

// k_build with fused bucket-base scan (per-block redundant reduce of totals[0..k))
__global__ __launch_bounds__(256) void k_build(const int* __restrict__ pairsG, const int* __restrict__ cntT,
                                               const int* __restrict__ scanT, const int* __restrict__ totals,
                                               int epb, int n, int nb,
                                               int* __restrict__ rowptr, int* __restrict__ colG, float* __restrict__ dinvG) {
  __shared__ int lpair[BCAP];
  __shared__ int lcol[BCAP];
  __shared__ int lcnt[128], lcur[128];
  __shared__ int tmp[256];
  __shared__ int bbs;
  int k = blockIdx.x, tid = threadIdx.x;
  // bb = sum totals[0..k)
  {
    int part = 0;
    for (int i = tid; i < k; i += 256) part += totals[i];
    tmp[tid] = part; __syncthreads();
    for (int s = 128; s > 0; s >>= 1) {
      if (tid < s) tmp[tid] += tmp[tid + s];
      __syncthreads();
    }
    if (tid == 0) bbs = tmp[0];
    __syncthreads();
  }
  int bb = bbs;
  int len = cntT[tid * 1024 + k];
  int sbase = tid * epb + scanT[tid * 1024 + k];
  tmp[tid] = len; __syncthreads();
  for (int off = 1; off < 256; off <<= 1) {
    int t = (tid >= off) ? tmp[tid - off] : 0; __syncthreads();
    tmp[tid] += t; __syncthreads();
  }
  int dpos = tmp[tid] - len;
  int cnt = tmp[255];
  for (int i = 0; i < len; ++i) lpair[dpos + i] = pairsG[sbase + i];
  if (tid < 128) lcnt[tid] = 0;
  __syncthreads();
  for (int j = tid; j < cnt; j += 256) atomicAdd(&lcnt[((unsigned)lpair[j]) >> 25], 1);
  __syncthreads();
  if (tid < 128) tmp[tid] = lcnt[tid];
  __syncthreads();
  for (int off = 1; off < 128; off <<= 1) {
    int t = (tid >= off && tid < 128) ? tmp[tid - off] : 0; __syncthreads();
    if (tid < 128) tmp[tid] += t;
    __syncthreads();
  }
  if (tid < 128) {
    int excl = tmp[tid] - lcnt[tid];
    lcur[tid] = excl;
    int g = k * 128 + tid;
    if (g < n) {
      rowptr[g] = bb + excl;
      dinvG[g] = rsqrtf((float)lcnt[tid] + 1.0f);
    }
  }
  if (k == nb - 1 && tid == 0) rowptr[n] = bb + cnt;
  __syncthreads();
  for (int j = tid; j < cnt; j += 256) {
    int w = lpair[j];
    int p = atomicAdd(&lcur[((unsigned)w) >> 25], 1);
    lcol[p] = w & 0x01FFFFFF;
  }
  __syncthreads();
  for (int j = tid; j < cnt; j += 256) colG[bb + j] = lcol[j];
}

// ---------------- MFMA GEMM: C(slab layout) = dinv[r]*(A @ Wt^T), K=128 ----------------
// C stored as 8 slabs of 16 feats: C + ni*n*16 + r*16 + c.  A direct-from-global.
// MODE 0: f32 src.  MODE 1: bf16 slab-layout src + fused BN from stat banks.
template <int MODE>
__global__ __launch_bounds__(256) void k_gemm128(const void* __restrict__ Ap, const unsigned short* __restrict__ Bt,
                                                 const float* __restrict__ bank, const float* __restrict__ gamma,
                                                 const float* __restrict__ beta, float invN,
                                                 const float* __restrict__ dinv, unsigned short* __restrict__ C, int n) {
  __shared__ unsigned short Bs[128 * 128];
  __shared__ float ssl[256];
  const int tid = threadIdx.x;
  const int row0 = blockIdx.x * 128;
  if (MODE == 1 && tid < 128) {     // fused bnfinal (redundant per block, L2-hot)
    float s = 0.f, q = 0.f;
    for (int b = 0; b < NBANK; ++b) { s += bank[b * 256 + tid]; q += bank[b * 256 + 128 + tid]; }
    float m = s * invN, var = q * invN - m * m;
    float sc = gamma[tid] * rsqrtf(var + BN_EPS);
    ssl[tid] = sc; ssl[128 + tid] = beta[tid] - m * sc;
  }
  {
    int colr = tid >> 1;
    int cbase = (tid & 1) * 8;
#pragma unroll
    for (int i = 0; i < 8; ++i) {
      int c16 = (cbase + i) * 16;
      int dstb = colr * 256 + (c16 ^ ((colr & 7) << 4));
      ushort8 v = *reinterpret_cast<const ushort8*>(Bt + colr * 128 + (c16 >> 1));
      *reinterpret_cast<ushort8*>((char*)Bs + dstb) = v;
    }
  }
  __syncthreads();

  const int wv = tid >> 6, l = tid & 63, lr = l & 15, lk = l >> 4;
  int rowc[2];
#pragma unroll
  for (int mi = 0; mi < 2; ++mi) {
    int gr = row0 + wv * 32 + mi * 16 + lr;
    rowc[mi] = (gr < n) ? gr : 0;
  }

  bf16x8 aF[2][4];
  if (MODE == 0) {
    const float* A = (const float*)Ap;
#pragma unroll
    for (int mi = 0; mi < 2; ++mi)
#pragma unroll
      for (int kt = 0; kt < 4; ++kt) {
        const float* p = A + (size_t)rowc[mi] * 128 + kt * 32 + lk * 8;
        f32x4 lo = *reinterpret_cast<const f32x4*>(p);
        f32x4 hi = *reinterpret_cast<const f32x4*>(p + 4);
        bf16x8 a;
#pragma unroll
        for (int j = 0; j < 4; ++j) { a[j] = (short)f2bf(lo[j]); a[4 + j] = (short)f2bf(hi[j]); }
        aF[mi][kt] = a;
      }
  } else {
    const unsigned short* A = (const unsigned short*)Ap;
    ushort8 raw[2][4];
#pragma unroll
    for (int mi = 0; mi < 2; ++mi)
#pragma unroll
      for (int kt = 0; kt < 4; ++kt) {
        int slab = kt * 2 + (lk >> 1);
        raw[mi][kt] = *reinterpret_cast<const ushort8*>(A + (size_t)slab * n * 16 + (size_t)rowc[mi] * 16 + (lk & 1) * 8);
      }
#pragma unroll
    for (int kt = 0; kt < 4; ++kt) {
      int kof = kt * 32 + lk * 8;
      float sc[8], sh[8];
#pragma unroll
      for (int j = 0; j < 8; ++j) { sc[j] = ssl[kof + j]; sh[j] = ssl[128 + kof + j]; }
#pragma unroll
      for (int mi = 0; mi < 2; ++mi) {
        bf16x8 a;
#pragma unroll
        for (int j = 0; j < 8; ++j) a[j] = (short)f2bf(bf2f(raw[mi][kt][j]) * sc[j] + sh[j]);
        aF[mi][kt] = a;
      }
    }
  }

  f32x4 acc[2][8];
#pragma unroll
  for (int mi = 0; mi < 2; ++mi)
#pragma unroll
    for (int ni = 0; ni < 8; ++ni) acc[mi][ni] = (f32x4)0.f;

#pragma unroll
  for (int kt = 0; kt < 4; ++kt) {
    int kbyte = kt * 64 + lk * 16;
    bf16x8 bF[8];
#pragma unroll
    for (int ni = 0; ni < 8; ++ni) {
      int c = ni * 16 + lr;
      bF[ni] = *reinterpret_cast<bf16x8*>((char*)Bs + c * 256 + (kbyte ^ ((c & 7) << 4)));
    }
#pragma unroll
    for (int mi = 0; mi < 2; ++mi)
#pragma unroll
      for (int ni = 0; ni < 8; ++ni)
        acc[mi][ni] = __builtin_amdgcn_mfma_f32_16x16x32_bf16(aF[mi][kt], bF[ni], acc[mi][ni], 0, 0, 0);
  }

#pragma unroll
  for (int mi = 0; mi < 2; ++mi) {
#pragma unroll
    for (int i = 0; i < 4; ++i) {
      int gr = row0 + wv * 32 + mi * 16 + lk * 4 + i;
      if (gr < n) {
        float di = dinv[gr];
#pragma unroll
        for (int ni = 0; ni < 8; ++ni)
          C[(size_t)ni * n * 16 + (size_t)gr * 16 + lr] = f2bf(acc[mi][ni][i] * di);
      }
    }
  }
}

// ---------------- MFMA GEMM3: t3(4 slabs of 16) = dinv*([x | bn(a1) | bn(a2)] @ Wt3^T), K=384 ----------------
__global__ __launch_bounds__(256) void k_gemm3(const float* __restrict__ x, const unsigned short* __restrict__ a1,
                                               const unsigned short* __restrict__ a2,
                                               const float* __restrict__ bank1, const float* __restrict__ bank2,
                                               const float* __restrict__ gamma, const float* __restrict__ beta,
                                               float invN,
                                               const unsigned short* __restrict__ Bt3, const float* __restrict__ dinv,
                                               unsigned short* __restrict__ C, int n) {
  __shared__ unsigned short Bs[64 * 384];
  __shared__ float ssl[512];
  const int tid = threadIdx.x;
  const int row0 = blockIdx.x * 128;
  if (tid < 256) {
    int f = tid & 127;
    const float* bk = (tid < 128) ? bank1 : bank2;
    int base = (tid < 128) ? 0 : 256;
    float s = 0.f, q = 0.f;
    for (int b = 0; b < NBANK; ++b) { s += bk[b * 256 + f]; q += bk[b * 256 + 128 + f]; }
    float m = s * invN, var = q * invN - m * m;
    float sc = gamma[f] * rsqrtf(var + BN_EPS);
    ssl[base + f] = sc; ssl[base + 128 + f] = beta[f] - m * sc;
  }
  {
    int colr = tid >> 2;
    int cb = tid & 3;
#pragma unroll
    for (int i = 0; i < 12; ++i) {
      int c16 = (cb + 4 * i) * 16;
      int dstb = colr * 768 + (c16 ^ ((colr & 7) << 4));
      ushort8 v = *reinterpret_cast<const ushort8*>(Bt3 + colr * 384 + (c16 >> 1));
      *reinterpret_cast<ushort8*>((char*)Bs + dstb) = v;
    }
  }
  __syncthreads();

  const int wv = tid >> 6, l = tid & 63, lr = l & 15, lk = l >> 4;
  int rowc[2];
#pragma unroll
  for (int mi = 0; mi < 2; ++mi) {
    int gr = row0 + wv * 32 + mi * 16 + lr;
    rowc[mi] = (gr < n) ? gr : 0;
  }

  f32x4 acc[2][4];
#pragma unroll
  for (int mi = 0; mi < 2; ++mi)
#pragma unroll
    for (int ni = 0; ni < 4; ++ni) acc[mi][ni] = (f32x4)0.f;

#pragma unroll
  for (int ch = 0; ch < 3; ++ch) {
    bf16x8 aF[2][4];
    if (ch == 0) {
#pragma unroll
      for (int mi = 0; mi < 2; ++mi)
#pragma unroll
        for (int kt = 0; kt < 4; ++kt) {
          const float* p = x + (size_t)rowc[mi] * 128 + kt * 32 + lk * 8;
          f32x4 lo = *reinterpret_cast<const f32x4*>(p);
          f32x4 hi = *reinterpret_cast<const f32x4*>(p + 4);
          bf16x8 a;
#pragma unroll
          for (int j = 0; j < 4; ++j) { a[j] = (short)f2bf(lo[j]); a[4 + j] = (short)f2bf(hi[j]); }
          aF[mi][kt] = a;
        }
    } else {
      const unsigned short* A = (ch == 1) ? a1 : a2;
      int base = (ch == 1) ? 0 : 256;
      ushort8 raw[2][4];
#pragma unroll
      for (int mi = 0; mi < 2; ++mi)
#pragma unroll
        for (int kt = 0; kt < 4; ++kt) {
          int slab = kt * 2 + (lk >> 1);
          raw[mi][kt] = *reinterpret_cast<const ushort8*>(A + (size_t)slab * n * 16 + (size_t)rowc[mi] * 16 + (lk & 1) * 8);
        }
#pragma unroll
      for (int kt = 0; kt < 4; ++kt) {
        int kof = kt * 32 + lk * 8;
        float sc[8], sh[8];
#pragma unroll
        for (int j = 0; j < 8; ++j) { sc[j] = ssl[base + kof + j]; sh[j] = ssl[base + 128 + kof + j]; }
#pragma unroll
        for (int mi = 0; mi < 2; ++mi) {
          bf16x8 a;
#pragma unroll
          for (int j = 0; j < 8; ++j) a[j] = (short)f2bf(bf2f(raw[mi][kt][j]) * sc[j] + sh[j]);
          aF[mi][kt] = a;
        }
      }
    }
#pragma unroll
    for (int kt = 0; kt < 4; ++kt) {
      int kbyteB = ch * 256 + kt * 64 + lk * 16;
      bf16x8 bF[4];
#pragma unroll
      for (int ni = 0; ni < 4; ++ni) {
        int c = ni * 16 + lr;
        bF[ni] = *reinterpret_cast<bf16x8*>((char*)Bs + c * 768 + (kbyteB ^ ((c & 7) << 4)));
      }
#pragma unroll
      for (int mi = 0; mi < 2; ++mi)
#pragma unroll
        for (int ni = 0; ni < 4; ++ni)
          acc[mi][ni] = __builtin_amdgcn_mfma_f32_16x16x32_bf16(aF[mi][kt], bF[ni], acc[mi][ni], 0, 0, 0);
    }
  }

#pragma unroll
  for (int mi = 0; mi < 2; ++mi) {
#pragma unroll
    for (int i = 0; i < 4; ++i) {
      int gr = row0 + wv * 32 + mi * 16 + lk * 4 + i;
      if (gr < n) {
        float di = dinv[gr];
#pragma unroll
        for (int ni = 0; ni < 4; ++ni)
          C[(size_t)ni * n * 16 + (size_t)gr * 16 + lr] = f2bf(acc[mi][ni][i] * di);
      }
    }
  }
}

// ---------------- slab aggregation, 128 feats (8 slabs of 16), XCD-resident ----------------
// block: slab = bid&7, chunk = bid>>3 -> 128 rows; 2 threads/row (8 feats each).
template <int STATS>
__global__ __launch_bounds__(256) void k_agg128s(const unsigned short* __restrict__ t, const int* __restrict__ rowptr,
                                                 const int* __restrict__ col, const float* __restrict__ dinv,
                                                 const float* __restrict__ bias, unsigned short* __restrict__ outp,
                                                 float* __restrict__ bank, int n) {
  int bid = blockIdx.x;
  int slab = bid & 7, chunk = bid >> 3;
  int tid = threadIdx.x;
  int g = tid >> 1, h = tid & 1;
  int r = chunk * 128 + g;
  const unsigned short* ts = t + (size_t)slab * n * 16;
  int hb = h * 8;
  float v[8];
#pragma unroll
  for (int j = 0; j < 8; ++j) v[j] = 0.f;
  if (r < n) {
    float di = dinv[r];
    int e = rowptr[r], e1 = rowptr[r + 1];
    float acc[8];
    {
      ushort8 sv = *reinterpret_cast<const ushort8*>(ts + (size_t)r * 16 + hb);
#pragma unroll
      for (int j = 0; j < 8; ++j) acc[j] = bf2f(sv[j]);
    }
    for (; e + 8 <= e1; e += 8) {
      int s0 = __builtin_nontemporal_load(col + e);
      int s1 = __builtin_nontemporal_load(col + e + 1);
      int s2 = __builtin_nontemporal_load(col + e + 2);
      int s3 = __builtin_nontemporal_load(col + e + 3);
      int s4 = __builtin_nontemporal_load(col + e + 4);
      int s5 = __builtin_nontemporal_load(col + e + 5);
      int s6 = __builtin_nontemporal_load(col + e + 6);
      int s7 = __builtin_nontemporal_load(col + e + 7);
      ushort8 u0 = *reinterpret_cast<const ushort8*>(ts + (size_t)s0 * 16 + hb);
      ushort8 u1 = *reinterpret_cast<const ushort8*>(ts + (size_t)s1 * 16 + hb);
      ushort8 u2 = *reinterpret_cast<const ushort8*>(ts + (size_t)s2 * 16 + hb);
      ushort8 u3 = *reinterpret_cast<const ushort8*>(ts + (size_t)s3 * 16 + hb);
      ushort8 u4 = *reinterpret_cast<const ushort8*>(ts + (size_t)s4 * 16 + hb);
      ushort8 u5 = *reinterpret_cast<const ushort8*>(ts + (size_t)s5 * 16 + hb);
      ushort8 u6 = *reinterpret_cast<const ushort8*>(ts + (size_t)s6 * 16 + hb);
      ushort8 u7 = *reinterpret_cast<const ushort8*>(ts + (size_t)s7 * 16 + hb);
#pragma unroll
      for (int j = 0; j < 8; ++j) {
        float p0 = bf2f(u0[j]) + bf2f(u1[j]);
        float p1 = bf2f(u2[j]) + bf2f(u3[j]);
        float p2 = bf2f(u4[j]) + bf2f(u5[j]);
        float p3 = bf2f(u6[j]) + bf2f(u7[j]);
        acc[j] += (p0 + p1) + (p2 + p3);
      }
    }
    for (; e < e1; ++e) {
      int s = __builtin_nontemporal_load(col + e);
      ushort8 u = *reinterpret_cast<const ushort8*>(ts + (size_t)s * 16 + hb);
#pragma unroll
      for (int j = 0; j < 8; ++j) acc[j] += bf2f(u[j]);
    }
#pragma unroll
    for (int j = 0; j < 8; ++j) v[j] = fmaxf(acc[j] * di + bias[slab * 16 + hb + j], 0.f);
    ushort8 ov;
#pragma unroll
    for (int j = 0; j < 8; ++j) ov[j] = f2bf(v[j]);
    *reinterpret_cast<ushort8*>(outp + (size_t)slab * n * 16 + (size_t)r * 16 + hb) = ov;
  }
  if (STATS) {
    __shared__ float sA[256 * 8];
    __shared__ float sB[256 * 8];
#pragma unroll
    for (int j = 0; j < 8; ++j) { sA[tid * 8 + j] = v[j]; sB[tid * 8 + j] = v[j] * v[j]; }
    __syncthreads();
    // reduce over g (rows) for fixed (h,j): tid = g*2+h
    for (int s = 64; s > 0; s >>= 1) {
      if (g < s) {
#pragma unroll
        for (int j = 0; j < 8; ++j) {
          sA[tid * 8 + j] += sA[(tid + 2 * s) * 8 + j];
          sB[tid * 8 + j] += sB[(tid + 2 * s) * 8 + j];
        }
      }
      __syncthreads();
    }
    if (g == 0) {   // tid 0 (h=0) and 1 (h=1)
      float* bk = bank + (chunk & (NBANK - 1)) * 256;
      int f = slab * 16 + hb;
#pragma unroll
      for (int j = 0; j < 8; ++j) {
        atomicAdd(&bk[f + j], sA[tid * 8 + j]);
        atomicAdd(&bk[128 + f + j], sB[tid * 8 + j]);
      }
    }
  }
}

// ---------------- slab aggregation, 64 feats (4 slabs of 16), f32 row-major out ----------------
// bid%8 = j: slab = j>>1, rowhalf = j&1; chunk = bid>>3 -> 256 rows.
__global__ __launch_bounds__(256) void k_agg64s(const unsigned short* __restrict__ t, const int* __restrict__ rowptr,
                                                const int* __restrict__ col, const float* __restrict__ dinv,
                                                const float* __restrict__ bias, float* __restrict__ outp, int n) {
  int bid = blockIdx.x;
  int jj = bid & 7, chunk = bid >> 3;
  int slab = jj >> 1, rh = jj & 1;
  int tid = threadIdx.x;
  int g = tid >> 1, h = tid & 1;
  int r = chunk * 256 + rh * 128 + g;
  const unsigned short* ts = t + (size_t)slab * n * 16;
  int hb = h * 8;
  if (r >= n) return;
  float di = dinv[r];
  int e = rowptr[r], e1 = rowptr[r + 1];
  float acc[8];
  {
    ushort8 sv = *reinterpret_cast<const ushort8*>(ts + (size_t)r * 16 + hb);
#pragma unroll
    for (int j = 0; j < 8; ++j) acc[j] = bf2f(sv[j]);
  }
  for (; e + 8 <= e1; e += 8) {
    int s0 = __builtin_nontemporal_load(col + e);
    int s1 = __builtin_nontemporal_load(col + e + 1);
    int s2 = __builtin_nontemporal_load(col + e + 2);
    int s3 = __builtin_nontemporal_load(col + e + 3);
    int s4 = __builtin_nontemporal_load(col + e + 4);
    int s5 = __builtin_nontemporal_load(col + e + 5);
    int s6 = __builtin_nontemporal_load(col + e + 6);
    int s7 = __builtin_nontemporal_load(col + e + 7);
    ushort8 u0 = *reinterpret_cast<const ushort8*>(ts + (size_t)s0 * 16 + hb);
    ushort8 u1 = *reinterpret_cast<const ushort8*>(ts + (size_t)s1 * 16 + hb);
    ushort8 u2 = *reinterpret_cast<const ushort8*>(ts + (size_t)s2 * 16 + hb);
    ushort8 u3 = *reinterpret_cast<const ushort8*>(ts + (size_t)s3 * 16 + hb);
    ushort8 u4 = *reinterpret_cast<const ushort8*>(ts + (size_t)s4 * 16 + hb);
    ushort8 u5 = *reinterpret_cast<const ushort8*>(ts + (size_t)s5 * 16 + hb);
    ushort8 u6 = *reinterpret_cast<const ushort8*>(ts + (size_t)s6 * 16 + hb);
    ushort8 u7 = *reinterpret_cast<const ushort8*>(ts + (size_t)s7 * 16 + hb);
#pragma unroll
    for (int j = 0; j < 8; ++j) {
      float p0 = bf2f(u0[j]) + bf2f(u1[j]);
      float p1 = bf2f(u2[j]) + bf2f(u3[j]);
      float p2 = bf2f(u4[j]) + bf2f(u5[j]);
      float p3 = bf2f(u6[j]) + bf2f(u7[j]);
      acc[j] += (p0 + p1) + (p2 + p3);
    }
  }
  for (; e < e1; ++e) {
    int s = __builtin_nontemporal_load(col + e);
    ushort8 u = *reinterpret_cast<const ushort8*>(ts + (size_t)s * 16 + hb);
#pragma unroll
    for (int j = 0; j < 8; ++j) acc[j] += bf2f(u[j]);
  }
  int fg = slab * 16 + hb;
  float v[8];
#pragma unroll
  for (int j = 0; j < 8; ++j) v[j] = fmaxf(acc[j] * di + bias[fg + j], 0.f);
  float* o = outp + (size_t)r * 64 + fg;
  f32x4 w0 = {v[0], v[1], v[2], v[3]};
  f32x4 w1 = {v[4], v[5], v[6], v[7]};
  __builtin_nontemporal_store(w0, reinterpret_cast<f32x4*>(o));
  __builtin_nontemporal_store(w1, reinterpret_cast<f32x4*>(o + 4));
}

// ---------------- launch ----------------
extern "C" void kernel_launch(void* const* d_in, const int* in_sizes, int n_in,
                              void* d_out, int out_size, void* d_ws, size_t ws_size,
                              hipStream_t stream) {
  const float* x    = (const float*)d_in[0];
  const int*   ei   = (const int*)d_in[1];
  const float* W1   = (const float*)d_in[2];
  const float* b1   = (const float*)d_in[3];
  const float* W2   = (const float*)d_in[4];
  const float* b2   = (const float*)d_in[5];
  const float* Wout = (const float*)d_in[6];
  const float* bout = (const float*)d_in[7];
  const float* gamma= (const float*)d_in[8];
  const float* beta = (const float*)d_in[9];
  float* out = (float*)d_out;

  const int n = in_sizes[0] / 128;
  const int e = in_sizes[1] / 2;
  const int* src = ei;
  const int* dst = ei + e;
  const int nb = (n + 127) >> 7;
  const int epb = (e + NBLK - 1) / NBLK;

  char* ws = (char*)d_ws;
  size_t off = 0;
  auto alloc = [&](size_t bytes) -> void* {
    void* p = ws + off;
    off += (bytes + 255) & ~(size_t)255;
    return p;
  };
  int*   pairsG = (int*)alloc((size_t)NBLK * epb * 4);
  int*   cntT   = (int*)alloc((size_t)NBLK * 1024 * 4);
  int*   scanT  = (int*)alloc((size_t)NBLK * 1024 * 4);
  int*   totals = (int*)alloc(1024 * 4);          // totals+bank1+bank2 contiguous: one memset
  float* bank1  = (float*)alloc(NBANK * 256 * 4);
  float* bank2  = (float*)alloc(NBANK * 256 * 4);
  int*   rowptr = (int*)alloc(((size_t)n + 1) * 4);
  float* dinv   = (float*)alloc((size_t)n * 4);
  int*   col    = (int*)alloc((size_t)e * 4);
  unsigned short* Wt1 = (unsigned short*)alloc(128 * 128 * 2);
  unsigned short* Wt2 = (unsigned short*)alloc(128 * 128 * 2);
  unsigned short* Wt3 = (unsigned short*)alloc(384 * 64 * 2);
  unsigned short* t   = (unsigned short*)alloc((size_t)n * 128 * 2);
  unsigned short* a1  = (unsigned short*)alloc((size_t)n * 128 * 2);
  unsigned short* a2  = (unsigned short*)alloc((size_t)n * 128 * 2);

  hipMemsetAsync(totals, 0, 1024 * 4 + (size_t)2 * NBANK * 256 * 4, stream);

  // graph build (+fused weight convert)
  k_part<<<NBLK + 224, 256, 0, stream>>>(src, dst, e, epb, pairsG, cntT, scanT, totals,
                                         W1, W2, Wout, Wt1, Wt2, Wt3);
  k_build<<<nb, 256, 0, stream>>>(pairsG, cntT, scanT, totals, epb, n, nb, rowptr, col, dinv);

  int nbG = (n + 127) / 128;
  int nbA128 = ((n + 127) / 128) * 8;
  int nbA64 = ((n + 255) / 256) * 8;
  float invN = 1.f / (float)n;

  // layer 1
  k_gemm128<0><<<nbG, 256, 0, stream>>>(x, Wt1, nullptr, nullptr, nullptr, invN, dinv, t, n);
  k_agg128s<1><<<nbA128, 256, 0, stream>>>(t, rowptr, col, dinv, b1, a1, bank1, n);

  // layer 2 (BN of a1 fused into A-load)
  k_gemm128<1><<<nbG, 256, 0, stream>>>(a1, Wt2, bank1, gamma, beta, invN, dinv, t, n);
  k_agg128s<1><<<nbA128, 256, 0, stream>>>(t, rowptr, col, dinv, b2, a2, bank2, n);

  // layer 3 (both BNs fused into A-load; t3 = 4 slabs of 16 in t)
  k_gemm3<<<nbG, 256, 0, stream>>>(x, a1, a2, bank1, bank2, gamma, beta, invN, Wt3, dinv, t, n);
  k_agg64s<<<nbA64, 256, 0, stream>>>(t, rowptr, col, dinv, bout, out, n);
}

// Round 8
// 299.592 us; speedup vs baseline: 1.5355x; 1.5355x over previous
//
#include <hip/hip_runtime.h>
#include <cstdint>
#include <cstddef>

#define BN_EPS 1e-5f
#define NBLK 256
#define EPBMAX 6400
#define BCAP 4096
#define NBANK 32

typedef __attribute__((ext_vector_type(8))) short  bf16x8;
typedef __attribute__((ext_vector_type(4))) float  f32x4;
typedef __attribute__((ext_vector_type(8))) unsigned short ushort8;

__device__ __forceinline__ float bf2f(unsigned short u) {
  union { unsigned int i; float f; } c; c.i = ((unsigned int)u) << 16; return c.f;
}
__device__ __forceinline__ unsigned short f2bf(float f) {
  union { float f; unsigned int i; } c; c.f = f;
  unsigned int u = c.i;
  return (unsigned short)((u + 0x7FFFu + ((u >> 16) & 1u)) >> 16);  // RNE
}

// ---------------- graph partition (+ fused weight-convert blocks) ----------------
__global__ __launch_bounds__(256) void k_part(const int* __restrict__ src, const int* __restrict__ dst, int e, int epb,
                                              int* __restrict__ pairsG, int* __restrict__ cntT, int* __restrict__ scanT,
                                              int* __restrict__ totals,
                                              const float* __restrict__ W1, const float* __restrict__ W2,
                                              const float* __restrict__ W3,
                                              unsigned short* __restrict__ Wt1, unsigned short* __restrict__ Wt2,
                                              unsigned short* __restrict__ Wt3) {
  int b = blockIdx.x, tid = threadIdx.x;
  if (b >= NBLK) {           // fused cvtw: f32 [K][N] -> bf16 [N][K]
    int bb = b - NBLK;
    if (bb < 64)       { int idx = bb * 256 + tid;        Wt1[(idx & 127) * 128 + (idx >> 7)] = f2bf(W1[idx]); }
    else if (bb < 128) { int idx = (bb - 64) * 256 + tid; Wt2[(idx & 127) * 128 + (idx >> 7)] = f2bf(W2[idx]); }
    else               { int idx = (bb - 128) * 256 + tid; Wt3[(idx & 63) * 384 + (idx >> 6)] = f2bf(W3[idx]); }
    return;
  }
  __shared__ int sbuf[EPBMAX];
  __shared__ int hist[1024];
  __shared__ int base[1024];
  __shared__ int tmp[256];
  int e0 = b * epb, e1 = min(e0 + epb, e);
  for (int i = tid; i < 1024; i += 256) hist[i] = 0;
  __syncthreads();
  for (int i = e0 + tid; i < e1; i += 256) atomicAdd(&hist[dst[i] >> 7], 1);
  __syncthreads();
  for (int i = tid; i < 1024; i += 256) { int h = hist[i]; if (h) atomicAdd(&totals[i], h); }
  int c0 = hist[tid * 4], c1 = hist[tid * 4 + 1], c2 = hist[tid * 4 + 2], c3 = hist[tid * 4 + 3];
  int lsum = c0 + c1 + c2 + c3;
  tmp[tid] = lsum; __syncthreads();
  for (int off = 1; off < 256; off <<= 1) {
    int t = (tid >= off) ? tmp[tid - off] : 0; __syncthreads();
    tmp[tid] += t; __syncthreads();
  }
  int excl = tmp[tid] - lsum;
  base[tid * 4] = excl; base[tid * 4 + 1] = excl + c0;
  base[tid * 4 + 2] = excl + c0 + c1; base[tid * 4 + 3] = excl + c0 + c1 + c2;
  *(int4*)(cntT + b * 1024 + tid * 4) = make_int4(c0, c1, c2, c3);
  *(int4*)(scanT + b * 1024 + tid * 4) = make_int4(base[tid * 4], base[tid * 4 + 1], base[tid * 4 + 2], base[tid * 4 + 3]);
  __syncthreads();
  for (int i = e0 + tid; i < e1; i += 256) {
    int d = dst[i], s = src[i];
    int p = atomicAdd(&base[d >> 7], 1);
    sbuf[p] = ((d & 127) << 25) | s;
  }
  __syncthreads();
  int cnt = e1 - e0;
  for (int i = tid; i < cnt; i += 256) pairsG[e0 + i] = sbuf[i];
}

// k_build: fused bucket-base scan + wave-cooperative segment gather
__global__ __launch_bounds__(256) void k_build(const int* __restrict__ pairsG, const int* __restrict__ cntT,
                                               const int* __restrict__ scanT, const int* __restrict__ totals,
                                               int epb, int n, int nb,
                                               int* __restrict__ rowptr, int* __restrict__ colG, float* __restrict__ dinvG) {
  __shared__ int lpair[BCAP];
  __shared__ int lcol[BCAP];
  __shared__ int lcnt[128], lcur[128];
  __shared__ int tmp[256];
  __shared__ int lenS[256], sbaseS[256], dposS[256];
  __shared__ int bbs;
  int k = blockIdx.x, tid = threadIdx.x;
  // bb = sum totals[0..k)
  {
    int part = 0;
    for (int i = tid; i < k; i += 256) part += totals[i];
    tmp[tid] = part; __syncthreads();
    for (int s = 128; s > 0; s >>= 1) {
      if (tid < s) tmp[tid] += tmp[tid + s];
      __syncthreads();
    }
    if (tid == 0) bbs = tmp[0];
    __syncthreads();
  }
  int bb = bbs;
  int len = cntT[tid * 1024 + k];
  int sbase = tid * epb + scanT[tid * 1024 + k];
  __syncthreads();
  tmp[tid] = len; __syncthreads();
  for (int off = 1; off < 256; off <<= 1) {
    int t = (tid >= off) ? tmp[tid - off] : 0; __syncthreads();
    tmp[tid] += t; __syncthreads();
  }
  int dpos = tmp[tid] - len;
  int cnt = tmp[255];
  lenS[tid] = len; sbaseS[tid] = sbase; dposS[tid] = dpos;
  if (tid < 128) lcnt[tid] = 0;
  __syncthreads();
  // wave-cooperative segment copy: wave w handles segments w, w+4, ...
  {
    int wv = tid >> 6, lane = tid & 63;
    for (int s = wv; s < 256; s += 4) {
      int L = lenS[s], sb = sbaseS[s], dp = dposS[s];
      for (int i = lane; i < L; i += 64) lpair[dp + i] = pairsG[sb + i];
    }
  }
  __syncthreads();
  for (int j = tid; j < cnt; j += 256) atomicAdd(&lcnt[((unsigned)lpair[j]) >> 25], 1);
  __syncthreads();
  if (tid < 128) tmp[tid] = lcnt[tid];
  __syncthreads();
  for (int off = 1; off < 128; off <<= 1) {
    int t = (tid >= off && tid < 128) ? tmp[tid - off] : 0; __syncthreads();
    if (tid < 128) tmp[tid] += t;
    __syncthreads();
  }
  if (tid < 128) {
    int excl = tmp[tid] - lcnt[tid];
    lcur[tid] = excl;
    int g = k * 128 + tid;
    if (g < n) {
      rowptr[g] = bb + excl;
      dinvG[g] = rsqrtf((float)lcnt[tid] + 1.0f);
    }
  }
  if (k == nb - 1 && tid == 0) rowptr[n] = bb + cnt;
  __syncthreads();
  for (int j = tid; j < cnt; j += 256) {
    int w = lpair[j];
    int p = atomicAdd(&lcur[((unsigned)w) >> 25], 1);
    lcol[p] = w & 0x01FFFFFF;
  }
  __syncthreads();
  for (int j = tid; j < cnt; j += 256) colG[bb + j] = lcol[j];
}

// ---------------- MFMA GEMM: C[n,128](bf16) = dinv[r]*(A @ Wt^T), K=128 ----------------
// A direct-from-global. MODE 0: f32 src. MODE 1: bf16 src + fused BN from stat banks.
template <int MODE>
__global__ __launch_bounds__(256) void k_gemm128(const void* __restrict__ Ap, const unsigned short* __restrict__ Bt,
                                                 const float* __restrict__ bank, const float* __restrict__ gamma,
                                                 const float* __restrict__ beta, float invN,
                                                 const float* __restrict__ dinv, unsigned short* __restrict__ C, int n) {
  __shared__ unsigned short Bs[128 * 128];
  __shared__ float ssl[256];
  const int tid = threadIdx.x;
  const int row0 = blockIdx.x * 128;
  if (MODE == 1 && tid < 128) {     // fused bnfinal (redundant per block, L2-hot)
    float s = 0.f, q = 0.f;
    for (int b = 0; b < NBANK; ++b) { s += bank[b * 256 + tid]; q += bank[b * 256 + 128 + tid]; }
    float m = s * invN, var = q * invN - m * m;
    float sc = gamma[tid] * rsqrtf(var + BN_EPS);
    ssl[tid] = sc; ssl[128 + tid] = beta[tid] - m * sc;
  }
  {
    int colr = tid >> 1;
    int cbase = (tid & 1) * 8;
#pragma unroll
    for (int i = 0; i < 8; ++i) {
      int c16 = (cbase + i) * 16;
      int dstb = colr * 256 + (c16 ^ ((colr & 7) << 4));
      ushort8 v = *reinterpret_cast<const ushort8*>(Bt + colr * 128 + (c16 >> 1));
      *reinterpret_cast<ushort8*>((char*)Bs + dstb) = v;
    }
  }
  __syncthreads();

  const int wv = tid >> 6, l = tid & 63, lr = l & 15, lk = l >> 4;
  int rowc[2];
#pragma unroll
  for (int mi = 0; mi < 2; ++mi) {
    int gr = row0 + wv * 32 + mi * 16 + lr;
    rowc[mi] = (gr < n) ? gr : 0;    // clamp; masked at write
  }

  bf16x8 aF[2][4];
  if (MODE == 0) {
    const float* A = (const float*)Ap;
#pragma unroll
    for (int mi = 0; mi < 2; ++mi)
#pragma unroll
      for (int kt = 0; kt < 4; ++kt) {
        const float* p = A + (size_t)rowc[mi] * 128 + kt * 32 + lk * 8;
        f32x4 lo = *reinterpret_cast<const f32x4*>(p);
        f32x4 hi = *reinterpret_cast<const f32x4*>(p + 4);
        bf16x8 a;
#pragma unroll
        for (int j = 0; j < 4; ++j) { a[j] = (short)f2bf(lo[j]); a[4 + j] = (short)f2bf(hi[j]); }
        aF[mi][kt] = a;
      }
  } else {
    const unsigned short* A = (const unsigned short*)Ap;
    ushort8 raw[2][4];
#pragma unroll
    for (int mi = 0; mi < 2; ++mi)
#pragma unroll
      for (int kt = 0; kt < 4; ++kt)
        raw[mi][kt] = *reinterpret_cast<const ushort8*>(A + (size_t)rowc[mi] * 128 + kt * 32 + lk * 8);
#pragma unroll
    for (int kt = 0; kt < 4; ++kt) {
      int kof = kt * 32 + lk * 8;
      float sc[8], sh[8];
#pragma unroll
      for (int j = 0; j < 8; ++j) { sc[j] = ssl[kof + j]; sh[j] = ssl[128 + kof + j]; }
#pragma unroll
      for (int mi = 0; mi < 2; ++mi) {
        bf16x8 a;
#pragma unroll
        for (int j = 0; j < 8; ++j) a[j] = (short)f2bf(bf2f(raw[mi][kt][j]) * sc[j] + sh[j]);
        aF[mi][kt] = a;
      }
    }
  }

  f32x4 acc[2][8];
#pragma unroll
  for (int mi = 0; mi < 2; ++mi)
#pragma unroll
    for (int ni = 0; ni < 8; ++ni) acc[mi][ni] = (f32x4)0.f;

#pragma unroll
  for (int kt = 0; kt < 4; ++kt) {
    int kbyte = kt * 64 + lk * 16;
    bf16x8 bF[8];
#pragma unroll
    for (int ni = 0; ni < 8; ++ni) {
      int c = ni * 16 + lr;
      bF[ni] = *reinterpret_cast<bf16x8*>((char*)Bs + c * 256 + (kbyte ^ ((c & 7) << 4)));
    }
#pragma unroll
    for (int mi = 0; mi < 2; ++mi)
#pragma unroll
      for (int ni = 0; ni < 8; ++ni)
        acc[mi][ni] = __builtin_amdgcn_mfma_f32_16x16x32_bf16(aF[mi][kt], bF[ni], acc[mi][ni], 0, 0, 0);
  }

#pragma unroll
  for (int mi = 0; mi < 2; ++mi) {
#pragma unroll
    for (int i = 0; i < 4; ++i) {
      int gr = row0 + wv * 32 + mi * 16 + lk * 4 + i;
      if (gr < n) {
        float di = dinv[gr];
#pragma unroll
        for (int ni = 0; ni < 8; ++ni) {
          int gc = ni * 16 + lr;
          C[(size_t)gr * 128 + gc] = f2bf(acc[mi][ni][i] * di);
        }
      }
    }
  }
}

// ---------------- MFMA GEMM3: C[n,64](bf16) = dinv*([x | bn(a1) | bn(a2)] @ Wt3^T), K=384 ----------------
__global__ __launch_bounds__(256) void k_gemm3(const float* __restrict__ x, const unsigned short* __restrict__ a1,
                                               const unsigned short* __restrict__ a2,
                                               const float* __restrict__ bank1, const float* __restrict__ bank2,
                                               const float* __restrict__ gamma, const float* __restrict__ beta,
                                               float invN,
                                               const unsigned short* __restrict__ Bt3, const float* __restrict__ dinv,
                                               unsigned short* __restrict__ C, int n) {
  __shared__ unsigned short Bs[64 * 384];   // 48KB
  __shared__ float ssl[512];                // [sc1|sh1|sc2|sh2]
  const int tid = threadIdx.x;
  const int row0 = blockIdx.x * 128;
  if (tid < 256) {
    int f = tid & 127;
    const float* bk = (tid < 128) ? bank1 : bank2;
    int base = (tid < 128) ? 0 : 256;
    float s = 0.f, q = 0.f;
    for (int b = 0; b < NBANK; ++b) { s += bk[b * 256 + f]; q += bk[b * 256 + 128 + f]; }
    float m = s * invN, var = q * invN - m * m;
    float sc = gamma[f] * rsqrtf(var + BN_EPS);
    ssl[base + f] = sc; ssl[base + 128 + f] = beta[f] - m * sc;
  }
  {
    int colr = tid >> 2;
    int cb = tid & 3;
#pragma unroll
    for (int i = 0; i < 12; ++i) {
      int c16 = (cb + 4 * i) * 16;
      int dstb = colr * 768 + (c16 ^ ((colr & 7) << 4));
      ushort8 v = *reinterpret_cast<const ushort8*>(Bt3 + colr * 384 + (c16 >> 1));
      *reinterpret_cast<ushort8*>((char*)Bs + dstb) = v;
    }
  }
  __syncthreads();

  const int wv = tid >> 6, l = tid & 63, lr = l & 15, lk = l >> 4;
  int rowc[2];
#pragma unroll
  for (int mi = 0; mi < 2; ++mi) {
    int gr = row0 + wv * 32 + mi * 16 + lr;
    rowc[mi] = (gr < n) ? gr : 0;
  }

  f32x4 acc[2][4];
#pragma unroll
  for (int mi = 0; mi < 2; ++mi)
#pragma unroll
    for (int ni = 0; ni < 4; ++ni) acc[mi][ni] = (f32x4)0.f;

#pragma unroll
  for (int ch = 0; ch < 3; ++ch) {
    bf16x8 aF[2][4];
    if (ch == 0) {
#pragma unroll
      for (int mi = 0; mi < 2; ++mi)
#pragma unroll
        for (int kt = 0; kt < 4; ++kt) {
          const float* p = x + (size_t)rowc[mi] * 128 + kt * 32 + lk * 8;
          f32x4 lo = *reinterpret_cast<const f32x4*>(p);
          f32x4 hi = *reinterpret_cast<const f32x4*>(p + 4);
          bf16x8 a;
#pragma unroll
          for (int j = 0; j < 4; ++j) { a[j] = (short)f2bf(lo[j]); a[4 + j] = (short)f2bf(hi[j]); }
          aF[mi][kt] = a;
        }
    } else {
      const unsigned short* A = (ch == 1) ? a1 : a2;
      int base = (ch == 1) ? 0 : 256;
      ushort8 raw[2][4];
#pragma unroll
      for (int mi = 0; mi < 2; ++mi)
#pragma unroll
        for (int kt = 0; kt < 4; ++kt)
          raw[mi][kt] = *reinterpret_cast<const ushort8*>(A + (size_t)rowc[mi] * 128 + kt * 32 + lk * 8);
#pragma unroll
      for (int kt = 0; kt < 4; ++kt) {
        int kof = kt * 32 + lk * 8;
        float sc[8], sh[8];
#pragma unroll
        for (int j = 0; j < 8; ++j) { sc[j] = ssl[base + kof + j]; sh[j] = ssl[base + 128 + kof + j]; }
#pragma unroll
        for (int mi = 0; mi < 2; ++mi) {
          bf16x8 a;
#pragma unroll
          for (int j = 0; j < 8; ++j) a[j] = (short)f2bf(bf2f(raw[mi][kt][j]) * sc[j] + sh[j]);
          aF[mi][kt] = a;
        }
      }
    }
#pragma unroll
    for (int kt = 0; kt < 4; ++kt) {
      int kbyteB = ch * 256 + kt * 64 + lk * 16;
      bf16x8 bF[4];
#pragma unroll
      for (int ni = 0; ni < 4; ++ni) {
        int c = ni * 16 + lr;
        bF[ni] = *reinterpret_cast<bf16x8*>((char*)Bs + c * 768 + (kbyteB ^ ((c & 7) << 4)));
      }
#pragma unroll
      for (int mi = 0; mi < 2; ++mi)
#pragma unroll
        for (int ni = 0; ni < 4; ++ni)
          acc[mi][ni] = __builtin_amdgcn_mfma_f32_16x16x32_bf16(aF[mi][kt], bF[ni], acc[mi][ni], 0, 0, 0);
    }
  }

#pragma unroll
  for (int mi = 0; mi < 2; ++mi) {
#pragma unroll
    for (int i = 0; i < 4; ++i) {
      int gr = row0 + wv * 32 + mi * 16 + lk * 4 + i;
      if (gr < n) {
        float di = dinv[gr];
#pragma unroll
        for (int ni = 0; ni < 4; ++ni) {
          int gc = ni * 16 + lr;
          C[(size_t)gr * 64 + gc] = f2bf(acc[mi][ni][i] * di);
        }
      }
    }
  }
}

// ---------------- aggregation (row-major, G=F/8 threads/row; at request-rate roofline) ----------------
template <int F, int STATS, int OUT_F32>
__global__ __launch_bounds__(256) void k_agg(const unsigned short* __restrict__ t, const int* __restrict__ rowptr,
                                             const int* __restrict__ col, const float* __restrict__ dinv,
                                             const float* __restrict__ bias, void* __restrict__ outp,
                                             float* __restrict__ bank, int n) {
  const int G = F / 8;
  const int RPB = 256 / G;
  int g = threadIdx.x / G;
  int c = threadIdx.x % G;
  int r = blockIdx.x * RPB + g;
  bool act = (r < n);
  float v[8];
#pragma unroll
  for (int j = 0; j < 8; ++j) v[j] = 0.f;
  int f0 = c * 8;
  if (act) {
    float di = dinv[r];
    int e = rowptr[r];
    int e1 = rowptr[r + 1];
    float acc[8];
    {
      ushort8 sv = *reinterpret_cast<const ushort8*>(t + (size_t)r * F + f0);
#pragma unroll
      for (int j = 0; j < 8; ++j) acc[j] = bf2f(sv[j]);
    }
    for (; e + 8 <= e1; e += 8) {
      int s0 = __builtin_nontemporal_load(col + e);
      int s1 = __builtin_nontemporal_load(col + e + 1);
      int s2 = __builtin_nontemporal_load(col + e + 2);
      int s3 = __builtin_nontemporal_load(col + e + 3);
      int s4 = __builtin_nontemporal_load(col + e + 4);
      int s5 = __builtin_nontemporal_load(col + e + 5);
      int s6 = __builtin_nontemporal_load(col + e + 6);
      int s7 = __builtin_nontemporal_load(col + e + 7);
      ushort8 u0 = *reinterpret_cast<const ushort8*>(t + (size_t)s0 * F + f0);
      ushort8 u1 = *reinterpret_cast<const ushort8*>(t + (size_t)s1 * F + f0);
      ushort8 u2 = *reinterpret_cast<const ushort8*>(t + (size_t)s2 * F + f0);
      ushort8 u3 = *reinterpret_cast<const ushort8*>(t + (size_t)s3 * F + f0);
      ushort8 u4 = *reinterpret_cast<const ushort8*>(t + (size_t)s4 * F + f0);
      ushort8 u5 = *reinterpret_cast<const ushort8*>(t + (size_t)s5 * F + f0);
      ushort8 u6 = *reinterpret_cast<const ushort8*>(t + (size_t)s6 * F + f0);
      ushort8 u7 = *reinterpret_cast<const ushort8*>(t + (size_t)s7 * F + f0);
#pragma unroll
      for (int j = 0; j < 8; ++j) {
        float p0 = bf2f(u0[j]) + bf2f(u1[j]);
        float p1 = bf2f(u2[j]) + bf2f(u3[j]);
        float p2 = bf2f(u4[j]) + bf2f(u5[j]);
        float p3 = bf2f(u6[j]) + bf2f(u7[j]);
        acc[j] += (p0 + p1) + (p2 + p3);
      }
    }
    if (e + 4 <= e1) {
      int s0 = col[e], s1 = col[e + 1], s2 = col[e + 2], s3 = col[e + 3];
      ushort8 u0 = *reinterpret_cast<const ushort8*>(t + (size_t)s0 * F + f0);
      ushort8 u1 = *reinterpret_cast<const ushort8*>(t + (size_t)s1 * F + f0);
      ushort8 u2 = *reinterpret_cast<const ushort8*>(t + (size_t)s2 * F + f0);
      ushort8 u3 = *reinterpret_cast<const ushort8*>(t + (size_t)s3 * F + f0);
#pragma unroll
      for (int j = 0; j < 8; ++j)
        acc[j] += (bf2f(u0[j]) + bf2f(u1[j])) + (bf2f(u2[j]) + bf2f(u3[j]));
      e += 4;
    }
    if (e + 2 <= e1) {
      int s0 = col[e], s1 = col[e + 1];
      ushort8 u0 = *reinterpret_cast<const ushort8*>(t + (size_t)s0 * F + f0);
      ushort8 u1 = *reinterpret_cast<const ushort8*>(t + (size_t)s1 * F + f0);
#pragma unroll
      for (int j = 0; j < 8; ++j) acc[j] += bf2f(u0[j]) + bf2f(u1[j]);
      e += 2;
    }
    if (e < e1) {
      int s = col[e];
      ushort8 u = *reinterpret_cast<const ushort8*>(t + (size_t)s * F + f0);
#pragma unroll
      for (int j = 0; j < 8; ++j) acc[j] += bf2f(u[j]);
    }
#pragma unroll
    for (int j = 0; j < 8; ++j) v[j] = fmaxf(acc[j] * di + bias[f0 + j], 0.f);
    if (OUT_F32) {
      float* o = (float*)outp;
#pragma unroll
      for (int j = 0; j < 8; j += 4) {
        f32x4 w = {v[j], v[j + 1], v[j + 2], v[j + 3]};
        __builtin_nontemporal_store(w, reinterpret_cast<f32x4*>(o + (size_t)r * F + f0 + j));
      }
    } else {
      ushort8 ov;
#pragma unroll
      for (int j = 0; j < 8; ++j) ov[j] = f2bf(v[j]);
      *reinterpret_cast<ushort8*>((unsigned short*)outp + (size_t)r * F + f0) = ov;
    }
  }
  if (STATS) {
    __shared__ float sA[256 * 8];
    __shared__ float sB[256 * 8];
#pragma unroll
    for (int j = 0; j < 8; ++j) { sA[threadIdx.x * 8 + j] = v[j]; sB[threadIdx.x * 8 + j] = v[j] * v[j]; }
    __syncthreads();
    if (threadIdx.x < 128) {
      int f = threadIdx.x;
      int cc = f >> 3, jj = f & 7;
      float s = 0.f, q = 0.f;
#pragma unroll
      for (int gg = 0; gg < 16; ++gg) {
        s += sA[(gg * 16 + cc) * 8 + jj];
        q += sB[(gg * 16 + cc) * 8 + jj];
      }
      float* bk = bank + (blockIdx.x & (NBANK - 1)) * 256;
      atomicAdd(&bk[f], s);
      atomicAdd(&bk[128 + f], q);
    }
  }
}

// ---------------- launch ----------------
extern "C" void kernel_launch(void* const* d_in, const int* in_sizes, int n_in,
                              void* d_out, int out_size, void* d_ws, size_t ws_size,
                              hipStream_t stream) {
  const float* x    = (const float*)d_in[0];
  const int*   ei   = (const int*)d_in[1];
  const float* W1   = (const float*)d_in[2];
  const float* b1   = (const float*)d_in[3];
  const float* W2   = (const float*)d_in[4];
  const float* b2   = (const float*)d_in[5];
  const float* Wout = (const float*)d_in[6];
  const float* bout = (const float*)d_in[7];
  const float* gamma= (const float*)d_in[8];
  const float* beta = (const float*)d_in[9];
  float* out = (float*)d_out;

  const int n = in_sizes[0] / 128;
  const int e = in_sizes[1] / 2;
  const int* src = ei;
  const int* dst = ei + e;
  const int nb = (n + 127) >> 7;
  const int epb = (e + NBLK - 1) / NBLK;

  char* ws = (char*)d_ws;
  size_t off = 0;
  auto alloc = [&](size_t bytes) -> void* {
    void* p = ws + off;
    off += (bytes + 255) & ~(size_t)255;
    return p;
  };
  int*   pairsG = (int*)alloc((size_t)NBLK * epb * 4);
  int*   cntT   = (int*)alloc((size_t)NBLK * 1024 * 4);
  int*   scanT  = (int*)alloc((size_t)NBLK * 1024 * 4);
  int*   totals = (int*)alloc(1024 * 4);          // totals+bank1+bank2 contiguous: one memset
  float* bank1  = (float*)alloc(NBANK * 256 * 4);
  float* bank2  = (float*)alloc(NBANK * 256 * 4);
  int*   rowptr = (int*)alloc(((size_t)n + 1) * 4);
  float* dinv   = (float*)alloc((size_t)n * 4);
  int*   col    = (int*)alloc((size_t)e * 4);
  unsigned short* Wt1 = (unsigned short*)alloc(128 * 128 * 2);
  unsigned short* Wt2 = (unsigned short*)alloc(128 * 128 * 2);
  unsigned short* Wt3 = (unsigned short*)alloc(384 * 64 * 2);
  unsigned short* t   = (unsigned short*)alloc((size_t)n * 128 * 2);
  unsigned short* a1  = (unsigned short*)alloc((size_t)n * 128 * 2);
  unsigned short* a2  = (unsigned short*)alloc((size_t)n * 128 * 2);

  hipMemsetAsync(totals, 0, 1024 * 4 + (size_t)2 * NBANK * 256 * 4, stream);

  // graph build (+fused weight convert)
  k_part<<<NBLK + 224, 256, 0, stream>>>(src, dst, e, epb, pairsG, cntT, scanT, totals,
                                         W1, W2, Wout, Wt1, Wt2, Wt3);
  k_build<<<nb, 256, 0, stream>>>(pairsG, cntT, scanT, totals, epb, n, nb, rowptr, col, dinv);

  int nbG = (n + 127) / 128;
  int nbA128 = (n + 15) / 16;
  int nbA64 = (n + 31) / 32;
  float invN = 1.f / (float)n;

  // layer 1
  k_gemm128<0><<<nbG, 256, 0, stream>>>(x, Wt1, nullptr, nullptr, nullptr, invN, dinv, t, n);
  k_agg<128, 1, 0><<<nbA128, 256, 0, stream>>>(t, rowptr, col, dinv, b1, a1, bank1, n);

  // layer 2 (BN of a1 fused into A-load)
  k_gemm128<1><<<nbG, 256, 0, stream>>>(a1, Wt2, bank1, gamma, beta, invN, dinv, t, n);
  k_agg<128, 1, 0><<<nbA128, 256, 0, stream>>>(t, rowptr, col, dinv, b2, a2, bank2, n);

  // layer 3 (both BNs fused into A-load)
  k_gemm3<<<nbG, 256, 0, stream>>>(x, a1, a2, bank1, bank2, gamma, beta, invN, Wt3, dinv, t, n);
  k_agg<64, 0, 1><<<nbA64, 256, 0, stream>>>(t, rowptr, col, dinv, bout, out, nullptr, n);
}

// Round 9
// 271.961 us; speedup vs baseline: 1.6915x; 1.1016x over previous
//
#include <hip/hip_runtime.h>
#include <cstdint>
#include <cstddef>

#define BN_EPS 1e-5f
#define NBLK 256
#define EPBMAX 6400
#define BCAP 4096
#define NBANK 32

typedef __attribute__((ext_vector_type(8))) short  bf16x8;
typedef __attribute__((ext_vector_type(4))) float  f32x4;
typedef __attribute__((ext_vector_type(8))) unsigned short ushort8;

__device__ __forceinline__ float bf2f(unsigned short u) {
  union { unsigned int i; float f; } c; c.i = ((unsigned int)u) << 16; return c.f;
}
__device__ __forceinline__ unsigned short f2bf(float f) {
  union { float f; unsigned int i; } c; c.f = f;
  unsigned int u = c.i;
  return (unsigned short)((u + 0x7FFFu + ((u >> 16) & 1u)) >> 16);  // RNE
}

// ---------------- graph partition (+ fused weight-convert blocks) ----------------
__global__ __launch_bounds__(256) void k_part(const int* __restrict__ src, const int* __restrict__ dst, int e, int epb,
                                              int* __restrict__ pairsG, int* __restrict__ cntT, int* __restrict__ scanT,
                                              int* __restrict__ totals,
                                              const float* __restrict__ W1, const float* __restrict__ W2,
                                              const float* __restrict__ W3,
                                              unsigned short* __restrict__ Wt1, unsigned short* __restrict__ Wt2,
                                              unsigned short* __restrict__ Wt3) {
  int b = blockIdx.x, tid = threadIdx.x;
  if (b >= NBLK) {           // fused cvtw: f32 [K][N] -> bf16 [N][K]
    int bb = b - NBLK;
    if (bb < 64)       { int idx = bb * 256 + tid;        Wt1[(idx & 127) * 128 + (idx >> 7)] = f2bf(W1[idx]); }
    else if (bb < 128) { int idx = (bb - 64) * 256 + tid; Wt2[(idx & 127) * 128 + (idx >> 7)] = f2bf(W2[idx]); }
    else               { int idx = (bb - 128) * 256 + tid; Wt3[(idx & 63) * 384 + (idx >> 6)] = f2bf(W3[idx]); }
    return;
  }
  __shared__ int sbuf[EPBMAX];
  __shared__ int hist[1024];
  __shared__ int base[1024];
  __shared__ int tmp[256];
  int e0 = b * epb, e1 = min(e0 + epb, e);
  for (int i = tid; i < 1024; i += 256) hist[i] = 0;
  __syncthreads();
  for (int i = e0 + tid; i < e1; i += 256) atomicAdd(&hist[dst[i] >> 7], 1);
  __syncthreads();
  for (int i = tid; i < 1024; i += 256) { int h = hist[i]; if (h) atomicAdd(&totals[i], h); }
  int c0 = hist[tid * 4], c1 = hist[tid * 4 + 1], c2 = hist[tid * 4 + 2], c3 = hist[tid * 4 + 3];
  int lsum = c0 + c1 + c2 + c3;
  tmp[tid] = lsum; __syncthreads();
  for (int off = 1; off < 256; off <<= 1) {
    int t = (tid >= off) ? tmp[tid - off] : 0; __syncthreads();
    tmp[tid] += t; __syncthreads();
  }
  int excl = tmp[tid] - lsum;
  base[tid * 4] = excl; base[tid * 4 + 1] = excl + c0;
  base[tid * 4 + 2] = excl + c0 + c1; base[tid * 4 + 3] = excl + c0 + c1 + c2;
  *(int4*)(cntT + b * 1024 + tid * 4) = make_int4(c0, c1, c2, c3);
  *(int4*)(scanT + b * 1024 + tid * 4) = make_int4(base[tid * 4], base[tid * 4 + 1], base[tid * 4 + 2], base[tid * 4 + 3]);
  __syncthreads();
  for (int i = e0 + tid; i < e1; i += 256) {
    int d = dst[i], s = src[i];
    int p = atomicAdd(&base[d >> 7], 1);
    sbuf[p] = ((d & 127) << 25) | s;
  }
  __syncthreads();
  int cnt = e1 - e0;
  for (int i = tid; i < cnt; i += 256) pairsG[e0 + i] = sbuf[i];
}

// k_build: fused bucket-base scan (per-block redundant, L2-hot) + per-thread segment copy
__global__ __launch_bounds__(256) void k_build(const int* __restrict__ pairsG, const int* __restrict__ cntT,
                                               const int* __restrict__ scanT, const int* __restrict__ totals,
                                               int epb, int n, int nb,
                                               int* __restrict__ rowptr, int* __restrict__ colG, float* __restrict__ dinvG) {
  __shared__ int lpair[BCAP];
  __shared__ int lcol[BCAP];
  __shared__ int lcnt[128], lcur[128];
  __shared__ int tmp[256];
  __shared__ int bbs;
  int k = blockIdx.x, tid = threadIdx.x;
  // bb = sum totals[0..k)
  {
    int part = 0;
    for (int i = tid; i < k; i += 256) part += totals[i];
    tmp[tid] = part; __syncthreads();
    for (int s = 128; s > 0; s >>= 1) {
      if (tid < s) tmp[tid] += tmp[tid + s];
      __syncthreads();
    }
    if (tid == 0) bbs = tmp[0];
    __syncthreads();
  }
  int bb = bbs;
  int len = cntT[tid * 1024 + k];
  int sbase = tid * epb + scanT[tid * 1024 + k];
  __syncthreads();
  tmp[tid] = len; __syncthreads();
  for (int off = 1; off < 256; off <<= 1) {
    int t = (tid >= off) ? tmp[tid - off] : 0; __syncthreads();
    tmp[tid] += t; __syncthreads();
  }
  int dpos = tmp[tid] - len;
  int cnt = tmp[255];
  for (int i = 0; i < len; ++i) lpair[dpos + i] = pairsG[sbase + i];
  if (tid < 128) lcnt[tid] = 0;
  __syncthreads();
  for (int j = tid; j < cnt; j += 256) atomicAdd(&lcnt[((unsigned)lpair[j]) >> 25], 1);
  __syncthreads();
  if (tid < 128) tmp[tid] = lcnt[tid];
  __syncthreads();
  for (int off = 1; off < 128; off <<= 1) {
    int t = (tid >= off && tid < 128) ? tmp[tid - off] : 0; __syncthreads();
    if (tid < 128) tmp[tid] += t;
    __syncthreads();
  }
  if (tid < 128) {
    int excl = tmp[tid] - lcnt[tid];
    lcur[tid] = excl;
    int g = k * 128 + tid;
    if (g < n) {
      rowptr[g] = bb + excl;
      dinvG[g] = rsqrtf((float)lcnt[tid] + 1.0f);
    }
  }
  if (k == nb - 1 && tid == 0) rowptr[n] = bb + cnt;
  __syncthreads();
  for (int j = tid; j < cnt; j += 256) {
    int w = lpair[j];
    int p = atomicAdd(&lcur[((unsigned)w) >> 25], 1);
    lcol[p] = w & 0x01FFFFFF;
  }
  __syncthreads();
  for (int j = tid; j < cnt; j += 256) colG[bb + j] = lcol[j];
}

// ---------------- MFMA GEMM: C[n,128](bf16) = dinv[r]*(A @ Wt^T), K=128 ----------------
// A direct-from-global. MODE 0: f32 src. MODE 1: bf16 src + fused BN from stat banks.
template <int MODE>
__global__ __launch_bounds__(256) void k_gemm128(const void* __restrict__ Ap, const unsigned short* __restrict__ Bt,
                                                 const float* __restrict__ bank, const float* __restrict__ gamma,
                                                 const float* __restrict__ beta, float invN,
                                                 const float* __restrict__ dinv, unsigned short* __restrict__ C, int n) {
  __shared__ unsigned short Bs[128 * 128];
  __shared__ float ssl[256];
  const int tid = threadIdx.x;
  const int row0 = blockIdx.x * 128;
  if (MODE == 1 && tid < 128) {     // fused bnfinal (redundant per block, L2-hot)
    float s = 0.f, q = 0.f;
    for (int b = 0; b < NBANK; ++b) { s += bank[b * 256 + tid]; q += bank[b * 256 + 128 + tid]; }
    float m = s * invN, var = q * invN - m * m;
    float sc = gamma[tid] * rsqrtf(var + BN_EPS);
    ssl[tid] = sc; ssl[128 + tid] = beta[tid] - m * sc;
  }
  {
    int colr = tid >> 1;
    int cbase = (tid & 1) * 8;
#pragma unroll
    for (int i = 0; i < 8; ++i) {
      int c16 = (cbase + i) * 16;
      int dstb = colr * 256 + (c16 ^ ((colr & 7) << 4));
      ushort8 v = *reinterpret_cast<const ushort8*>(Bt + colr * 128 + (c16 >> 1));
      *reinterpret_cast<ushort8*>((char*)Bs + dstb) = v;
    }
  }
  __syncthreads();

  const int wv = tid >> 6, l = tid & 63, lr = l & 15, lk = l >> 4;
  int rowc[2];
#pragma unroll
  for (int mi = 0; mi < 2; ++mi) {
    int gr = row0 + wv * 32 + mi * 16 + lr;
    rowc[mi] = (gr < n) ? gr : 0;    // clamp; masked at write
  }

  bf16x8 aF[2][4];
  if (MODE == 0) {
    const float* A = (const float*)Ap;
#pragma unroll
    for (int mi = 0; mi < 2; ++mi)
#pragma unroll
      for (int kt = 0; kt < 4; ++kt) {
        const float* p = A + (size_t)rowc[mi] * 128 + kt * 32 + lk * 8;
        f32x4 lo = *reinterpret_cast<const f32x4*>(p);
        f32x4 hi = *reinterpret_cast<const f32x4*>(p + 4);
        bf16x8 a;
#pragma unroll
        for (int j = 0; j < 4; ++j) { a[j] = (short)f2bf(lo[j]); a[4 + j] = (short)f2bf(hi[j]); }
        aF[mi][kt] = a;
      }
  } else {
    const unsigned short* A = (const unsigned short*)Ap;
    ushort8 raw[2][4];
#pragma unroll
    for (int mi = 0; mi < 2; ++mi)
#pragma unroll
      for (int kt = 0; kt < 4; ++kt)
        raw[mi][kt] = *reinterpret_cast<const ushort8*>(A + (size_t)rowc[mi] * 128 + kt * 32 + lk * 8);
#pragma unroll
    for (int kt = 0; kt < 4; ++kt) {
      int kof = kt * 32 + lk * 8;
      float sc[8], sh[8];
#pragma unroll
      for (int j = 0; j < 8; ++j) { sc[j] = ssl[kof + j]; sh[j] = ssl[128 + kof + j]; }
#pragma unroll
      for (int mi = 0; mi < 2; ++mi) {
        bf16x8 a;
#pragma unroll
        for (int j = 0; j < 8; ++j) a[j] = (short)f2bf(bf2f(raw[mi][kt][j]) * sc[j] + sh[j]);
        aF[mi][kt] = a;
      }
    }
  }

  f32x4 acc[2][8];
#pragma unroll
  for (int mi = 0; mi < 2; ++mi)
#pragma unroll
    for (int ni = 0; ni < 8; ++ni) acc[mi][ni] = (f32x4)0.f;

#pragma unroll
  for (int kt = 0; kt < 4; ++kt) {
    int kbyte = kt * 64 + lk * 16;
    bf16x8 bF[8];
#pragma unroll
    for (int ni = 0; ni < 8; ++ni) {
      int c = ni * 16 + lr;
      bF[ni] = *reinterpret_cast<bf16x8*>((char*)Bs + c * 256 + (kbyte ^ ((c & 7) << 4)));
    }
#pragma unroll
    for (int mi = 0; mi < 2; ++mi)
#pragma unroll
      for (int ni = 0; ni < 8; ++ni)
        acc[mi][ni] = __builtin_amdgcn_mfma_f32_16x16x32_bf16(aF[mi][kt], bF[ni], acc[mi][ni], 0, 0, 0);
  }

#pragma unroll
  for (int mi = 0; mi < 2; ++mi) {
#pragma unroll
    for (int i = 0; i < 4; ++i) {
      int gr = row0 + wv * 32 + mi * 16 + lk * 4 + i;
      if (gr < n) {
        float di = dinv[gr];
#pragma unroll
        for (int ni = 0; ni < 8; ++ni) {
          int gc = ni * 16 + lr;
          C[(size_t)gr * 128 + gc] = f2bf(acc[mi][ni][i] * di);
        }
      }
    }
  }
}

// ---------------- MFMA GEMM3: C[n,64](bf16) = dinv*([x | bn(a1) | bn(a2)] @ Wt3^T), K=384 ----------------
__global__ __launch_bounds__(256) void k_gemm3(const float* __restrict__ x, const unsigned short* __restrict__ a1,
                                               const unsigned short* __restrict__ a2,
                                               const float* __restrict__ bank1, const float* __restrict__ bank2,
                                               const float* __restrict__ gamma, const float* __restrict__ beta,
                                               float invN,
                                               const unsigned short* __restrict__ Bt3, const float* __restrict__ dinv,
                                               unsigned short* __restrict__ C, int n) {
  __shared__ unsigned short Bs[64 * 384];   // 48KB
  __shared__ float ssl[512];                // [sc1|sh1|sc2|sh2]
  const int tid = threadIdx.x;
  const int row0 = blockIdx.x * 128;
  if (tid < 256) {
    int f = tid & 127;
    const float* bk = (tid < 128) ? bank1 : bank2;
    int base = (tid < 128) ? 0 : 256;
    float s = 0.f, q = 0.f;
    for (int b = 0; b < NBANK; ++b) { s += bk[b * 256 + f]; q += bk[b * 256 + 128 + f]; }
    float m = s * invN, var = q * invN - m * m;
    float sc = gamma[f] * rsqrtf(var + BN_EPS);
    ssl[base + f] = sc; ssl[base + 128 + f] = beta[f] - m * sc;
  }
  {
    int colr = tid >> 2;
    int cb = tid & 3;
#pragma unroll
    for (int i = 0; i < 12; ++i) {
      int c16 = (cb + 4 * i) * 16;
      int dstb = colr * 768 + (c16 ^ ((colr & 7) << 4));
      ushort8 v = *reinterpret_cast<const ushort8*>(Bt3 + colr * 384 + (c16 >> 1));
      *reinterpret_cast<ushort8*>((char*)Bs + dstb) = v;
    }
  }
  __syncthreads();

  const int wv = tid >> 6, l = tid & 63, lr = l & 15, lk = l >> 4;
  int rowc[2];
#pragma unroll
  for (int mi = 0; mi < 2; ++mi) {
    int gr = row0 + wv * 32 + mi * 16 + lr;
    rowc[mi] = (gr < n) ? gr : 0;
  }

  f32x4 acc[2][4];
#pragma unroll
  for (int mi = 0; mi < 2; ++mi)
#pragma unroll
    for (int ni = 0; ni < 4; ++ni) acc[mi][ni] = (f32x4)0.f;

#pragma unroll
  for (int ch = 0; ch < 3; ++ch) {
    bf16x8 aF[2][4];
    if (ch == 0) {
#pragma unroll
      for (int mi = 0; mi < 2; ++mi)
#pragma unroll
        for (int kt = 0; kt < 4; ++kt) {
          const float* p = x + (size_t)rowc[mi] * 128 + kt * 32 + lk * 8;
          f32x4 lo = *reinterpret_cast<const f32x4*>(p);
          f32x4 hi = *reinterpret_cast<const f32x4*>(p + 4);
          bf16x8 a;
#pragma unroll
          for (int j = 0; j < 4; ++j) { a[j] = (short)f2bf(lo[j]); a[4 + j] = (short)f2bf(hi[j]); }
          aF[mi][kt] = a;
        }
    } else {
      const unsigned short* A = (ch == 1) ? a1 : a2;
      int base = (ch == 1) ? 0 : 256;
      ushort8 raw[2][4];
#pragma unroll
      for (int mi = 0; mi < 2; ++mi)
#pragma unroll
        for (int kt = 0; kt < 4; ++kt)
          raw[mi][kt] = *reinterpret_cast<const ushort8*>(A + (size_t)rowc[mi] * 128 + kt * 32 + lk * 8);
#pragma unroll
      for (int kt = 0; kt < 4; ++kt) {
        int kof = kt * 32 + lk * 8;
        float sc[8], sh[8];
#pragma unroll
        for (int j = 0; j < 8; ++j) { sc[j] = ssl[base + kof + j]; sh[j] = ssl[base + 128 + kof + j]; }
#pragma unroll
        for (int mi = 0; mi < 2; ++mi) {
          bf16x8 a;
#pragma unroll
          for (int j = 0; j < 8; ++j) a[j] = (short)f2bf(bf2f(raw[mi][kt][j]) * sc[j] + sh[j]);
          aF[mi][kt] = a;
        }
      }
    }
#pragma unroll
    for (int kt = 0; kt < 4; ++kt) {
      int kbyteB = ch * 256 + kt * 64 + lk * 16;
      bf16x8 bF[4];
#pragma unroll
      for (int ni = 0; ni < 4; ++ni) {
        int c = ni * 16 + lr;
        bF[ni] = *reinterpret_cast<bf16x8*>((char*)Bs + c * 768 + (kbyteB ^ ((c & 7) << 4)));
      }
#pragma unroll
      for (int mi = 0; mi < 2; ++mi)
#pragma unroll
        for (int ni = 0; ni < 4; ++ni)
          acc[mi][ni] = __builtin_amdgcn_mfma_f32_16x16x32_bf16(aF[mi][kt], bF[ni], acc[mi][ni], 0, 0, 0);
    }
  }

#pragma unroll
  for (int mi = 0; mi < 2; ++mi) {
#pragma unroll
    for (int i = 0; i < 4; ++i) {
      int gr = row0 + wv * 32 + mi * 16 + lk * 4 + i;
      if (gr < n) {
        float di = dinv[gr];
#pragma unroll
        for (int ni = 0; ni < 4; ++ni) {
          int gc = ni * 16 + lr;
          C[(size_t)gr * 64 + gc] = f2bf(acc[mi][ni][i] * di);
        }
      }
    }
  }
}

// ---------------- aggregation (row-major, G=F/8 threads/row; at request-rate roofline) ----------------
template <int F, int STATS, int OUT_F32>
__global__ __launch_bounds__(256) void k_agg(const unsigned short* __restrict__ t, const int* __restrict__ rowptr,
                                             const int* __restrict__ col, const float* __restrict__ dinv,
                                             const float* __restrict__ bias, void* __restrict__ outp,
                                             float* __restrict__ bank, int n) {
  const int G = F / 8;
  const int RPB = 256 / G;
  int g = threadIdx.x / G;
  int c = threadIdx.x % G;
  int r = blockIdx.x * RPB + g;
  bool act = (r < n);
  float v[8];
#pragma unroll
  for (int j = 0; j < 8; ++j) v[j] = 0.f;
  int f0 = c * 8;
  if (act) {
    float di = dinv[r];
    int e = rowptr[r];
    int e1 = rowptr[r + 1];
    float acc[8];
    {
      ushort8 sv = *reinterpret_cast<const ushort8*>(t + (size_t)r * F + f0);
#pragma unroll
      for (int j = 0; j < 8; ++j) acc[j] = bf2f(sv[j]);
    }
    for (; e + 8 <= e1; e += 8) {
      int s0 = col[e],     s1 = col[e + 1], s2 = col[e + 2], s3 = col[e + 3];
      int s4 = col[e + 4], s5 = col[e + 5], s6 = col[e + 6], s7 = col[e + 7];
      ushort8 u0 = *reinterpret_cast<const ushort8*>(t + (size_t)s0 * F + f0);
      ushort8 u1 = *reinterpret_cast<const ushort8*>(t + (size_t)s1 * F + f0);
      ushort8 u2 = *reinterpret_cast<const ushort8*>(t + (size_t)s2 * F + f0);
      ushort8 u3 = *reinterpret_cast<const ushort8*>(t + (size_t)s3 * F + f0);
      ushort8 u4 = *reinterpret_cast<const ushort8*>(t + (size_t)s4 * F + f0);
      ushort8 u5 = *reinterpret_cast<const ushort8*>(t + (size_t)s5 * F + f0);
      ushort8 u6 = *reinterpret_cast<const ushort8*>(t + (size_t)s6 * F + f0);
      ushort8 u7 = *reinterpret_cast<const ushort8*>(t + (size_t)s7 * F + f0);
#pragma unroll
      for (int j = 0; j < 8; ++j) {
        float p0 = bf2f(u0[j]) + bf2f(u1[j]);
        float p1 = bf2f(u2[j]) + bf2f(u3[j]);
        float p2 = bf2f(u4[j]) + bf2f(u5[j]);
        float p3 = bf2f(u6[j]) + bf2f(u7[j]);
        acc[j] += (p0 + p1) + (p2 + p3);
      }
    }
    if (e + 4 <= e1) {
      int s0 = col[e], s1 = col[e + 1], s2 = col[e + 2], s3 = col[e + 3];
      ushort8 u0 = *reinterpret_cast<const ushort8*>(t + (size_t)s0 * F + f0);
      ushort8 u1 = *reinterpret_cast<const ushort8*>(t + (size_t)s1 * F + f0);
      ushort8 u2 = *reinterpret_cast<const ushort8*>(t + (size_t)s2 * F + f0);
      ushort8 u3 = *reinterpret_cast<const ushort8*>(t + (size_t)s3 * F + f0);
#pragma unroll
      for (int j = 0; j < 8; ++j)
        acc[j] += (bf2f(u0[j]) + bf2f(u1[j])) + (bf2f(u2[j]) + bf2f(u3[j]));
      e += 4;
    }
    if (e + 2 <= e1) {
      int s0 = col[e], s1 = col[e + 1];
      ushort8 u0 = *reinterpret_cast<const ushort8*>(t + (size_t)s0 * F + f0);
      ushort8 u1 = *reinterpret_cast<const ushort8*>(t + (size_t)s1 * F + f0);
#pragma unroll
      for (int j = 0; j < 8; ++j) acc[j] += bf2f(u0[j]) + bf2f(u1[j]);
      e += 2;
    }
    if (e < e1) {
      int s = col[e];
      ushort8 u = *reinterpret_cast<const ushort8*>(t + (size_t)s * F + f0);
#pragma unroll
      for (int j = 0; j < 8; ++j) acc[j] += bf2f(u[j]);
    }
#pragma unroll
    for (int j = 0; j < 8; ++j) v[j] = fmaxf(acc[j] * di + bias[f0 + j], 0.f);
    if (OUT_F32) {
      float* o = (float*)outp;
#pragma unroll
      for (int j = 0; j < 8; j += 4) {
        f32x4 w = {v[j], v[j + 1], v[j + 2], v[j + 3]};
        __builtin_nontemporal_store(w, reinterpret_cast<f32x4*>(o + (size_t)r * F + f0 + j));
      }
    } else {
      ushort8 ov;
#pragma unroll
      for (int j = 0; j < 8; ++j) ov[j] = f2bf(v[j]);
      *reinterpret_cast<ushort8*>((unsigned short*)outp + (size_t)r * F + f0) = ov;
    }
  }
  if (STATS) {
    __shared__ float sA[256 * 8];
    __shared__ float sB[256 * 8];
#pragma unroll
    for (int j = 0; j < 8; ++j) { sA[threadIdx.x * 8 + j] = v[j]; sB[threadIdx.x * 8 + j] = v[j] * v[j]; }
    __syncthreads();
    if (threadIdx.x < 128) {
      int f = threadIdx.x;
      int cc = f >> 3, jj = f & 7;
      float s = 0.f, q = 0.f;
#pragma unroll
      for (int gg = 0; gg < 16; ++gg) {
        s += sA[(gg * 16 + cc) * 8 + jj];
        q += sB[(gg * 16 + cc) * 8 + jj];
      }
      float* bk = bank + (blockIdx.x & (NBANK - 1)) * 256;
      atomicAdd(&bk[f], s);
      atomicAdd(&bk[128 + f], q);
    }
  }
}

// ---------------- launch ----------------
extern "C" void kernel_launch(void* const* d_in, const int* in_sizes, int n_in,
                              void* d_out, int out_size, void* d_ws, size_t ws_size,
                              hipStream_t stream) {
  const float* x    = (const float*)d_in[0];
  const int*   ei   = (const int*)d_in[1];
  const float* W1   = (const float*)d_in[2];
  const float* b1   = (const float*)d_in[3];
  const float* W2   = (const float*)d_in[4];
  const float* b2   = (const float*)d_in[5];
  const float* Wout = (const float*)d_in[6];
  const float* bout = (const float*)d_in[7];
  const float* gamma= (const float*)d_in[8];
  const float* beta = (const float*)d_in[9];
  float* out = (float*)d_out;

  const int n = in_sizes[0] / 128;
  const int e = in_sizes[1] / 2;
  const int* src = ei;
  const int* dst = ei + e;
  const int nb = (n + 127) >> 7;
  const int epb = (e + NBLK - 1) / NBLK;

  char* ws = (char*)d_ws;
  size_t off = 0;
  auto alloc = [&](size_t bytes) -> void* {
    void* p = ws + off;
    off += (bytes + 255) & ~(size_t)255;
    return p;
  };
  int*   pairsG = (int*)alloc((size_t)NBLK * epb * 4);
  int*   cntT   = (int*)alloc((size_t)NBLK * 1024 * 4);
  int*   scanT  = (int*)alloc((size_t)NBLK * 1024 * 4);
  int*   totals = (int*)alloc(1024 * 4);          // totals+bank1+bank2 contiguous: one memset
  float* bank1  = (float*)alloc(NBANK * 256 * 4);
  float* bank2  = (float*)alloc(NBANK * 256 * 4);
  int*   rowptr = (int*)alloc(((size_t)n + 1) * 4);
  float* dinv   = (float*)alloc((size_t)n * 4);
  int*   col    = (int*)alloc((size_t)e * 4);
  unsigned short* Wt1 = (unsigned short*)alloc(128 * 128 * 2);
  unsigned short* Wt2 = (unsigned short*)alloc(128 * 128 * 2);
  unsigned short* Wt3 = (unsigned short*)alloc(384 * 64 * 2);
  unsigned short* t   = (unsigned short*)alloc((size_t)n * 128 * 2);
  unsigned short* a1  = (unsigned short*)alloc((size_t)n * 128 * 2);
  unsigned short* a2  = (unsigned short*)alloc((size_t)n * 128 * 2);

  hipMemsetAsync(totals, 0, 1024 * 4 + (size_t)2 * NBANK * 256 * 4, stream);

  // graph build (+fused weight convert)
  k_part<<<NBLK + 224, 256, 0, stream>>>(src, dst, e, epb, pairsG, cntT, scanT, totals,
                                         W1, W2, Wout, Wt1, Wt2, Wt3);
  k_build<<<nb, 256, 0, stream>>>(pairsG, cntT, scanT, totals, epb, n, nb, rowptr, col, dinv);

  int nbG = (n + 127) / 128;
  int nbA128 = (n + 15) / 16;
  int nbA64 = (n + 31) / 32;
  float invN = 1.f / (float)n;

  // layer 1
  k_gemm128<0><<<nbG, 256, 0, stream>>>(x, Wt1, nullptr, nullptr, nullptr, invN, dinv, t, n);
  k_agg<128, 1, 0><<<nbA128, 256, 0, stream>>>(t, rowptr, col, dinv, b1, a1, bank1, n);

  // layer 2 (BN of a1 fused into A-load)
  k_gemm128<1><<<nbG, 256, 0, stream>>>(a1, Wt2, bank1, gamma, beta, invN, dinv, t, n);
  k_agg<128, 1, 0><<<nbA128, 256, 0, stream>>>(t, rowptr, col, dinv, b2, a2, bank2, n);

  // layer 3 (both BNs fused into A-load)
  k_gemm3<<<nbG, 256, 0, stream>>>(x, a1, a2, bank1, bank2, gamma, beta, invN, Wt3, dinv, t, n);
  k_agg<64, 0, 1><<<nbA64, 256, 0, stream>>>(t, rowptr, col, dinv, bout, out, nullptr, n);
}